// Round 11
// baseline (78.439 us; speedup 1.0000x reference)
//
#include <hip/hip_runtime.h>

#define B_ 8
#define S_ 512
#define D_ 768
#define D4 (D_/4)                // 192 float4 per token vector
#define LAYER0 4
#define LSTRIDE4 (8*512*768/4)   // float4 between layers
#define SCH 32                   // pooling chunks per batch
#define CW (S_/SCH)              // 16 tokens per chunk

// upper-triangle pair q -> (i,j), i<=j, row-major
__device__ const int QI9[45] = {0,0,0,0,0,0,0,0,0, 1,1,1,1,1,1,1,1, 2,2,2,2,2,2,2,
                                3,3,3,3,3,3, 4,4,4,4,4, 5,5,5,5, 6,6,6, 7,7, 8};
__device__ const int QJ9[45] = {0,1,2,3,4,5,6,7,8, 1,2,3,4,5,6,7,8, 2,3,4,5,6,7,8,
                                3,4,5,6,7,8, 4,5,6,7,8, 5,6,7,8, 6,7,8, 7,8, 8};

__device__ __forceinline__ float dot4(const float4& a, const float4& b) {
  return fmaf(a.x, b.x, fmaf(a.y, b.y, fmaf(a.z, b.z, a.w * b.w)));
}

// ---------------- kernel 1: per-token Gram (f32) + alpha + weighted te ----------------
// EXACT round-6 structure (52.3 µs proven): 64 thr / 1 wave / f[27] / stride-45 pgl.
__global__ __launch_bounds__(64) void wk_token(const float* __restrict__ hid,
                                               const int* __restrict__ mask,
                                               float* __restrict__ wte,
                                               float* __restrict__ wv) {
  const int token = blockIdx.x;        // b*S + s
  const int b = token >> 9;
  const int s = token & (S_ - 1);
  const int t = threadIdx.x;           // 0..63, one wave

  __shared__ float pgl[64][45];        // stride 45: odd -> conflict-free writes
  __shared__ float Gsym[81];
  __shared__ float st[19];             // align[0..8], nov[9..17], var[18]

  // mask is monotone (arange < length): s < len=length-1  <=>  mask[s+1]==1
  const int valid = (s < S_ - 1) ? mask[b * S_ + s + 1] : 0;

  // each lane owns 12 dims: float4 indices t, t+64, t+128 (3 coalesced dwordx4 per layer)
  const float4* base = (const float4*)hid
      + (((size_t)LAYER0 * B_ + b) * S_ + s) * D4 + t;
  float4 f[27];
#pragma unroll
  for (int l = 0; l < 9; ++l) {
#pragma unroll
    for (int c = 0; c < 3; ++c) f[l * 3 + c] = base[(size_t)l * LSTRIDE4 + c * 64];
  }

  // 45 pair partial dots -> LDS
  {
    int q = 0;
#pragma unroll
    for (int i = 0; i < 9; ++i) {
#pragma unroll
      for (int j = i; j < 9; ++j) {
        pgl[t][q] = dot4(f[i * 3], f[j * 3])
                  + dot4(f[i * 3 + 1], f[j * 3 + 1])
                  + dot4(f[i * 3 + 2], f[j * 3 + 2]);
        ++q;
      }
    }
  }
  __syncthreads();

  // column sums: lane q (<45) owns pair q; 4 accumulators break the FP chain
  if (t < 45) {
    float a0 = 0.f, a1 = 0.f, a2 = 0.f, a3 = 0.f;
#pragma unroll
    for (int r = 0; r < 64; r += 4) {
      a0 += pgl[r][t];     a1 += pgl[r + 1][t];
      a2 += pgl[r + 2][t]; a3 += pgl[r + 3][t];
    }
    float tot = (a0 + a1) + (a2 + a3);
    Gsym[QI9[t] * 9 + QJ9[t]] = tot;
    Gsym[QJ9[t] * 9 + QI9[t]] = tot;
  }
  __syncthreads();

  // lanes 0..8: per-k align/nov via Cholesky; lane 9: cosine variance -> LDS
  if (t < 9) {
    const int k = t;
    int nb[4]; int m = 0;
    if (k >= 2) { nb[m++] = k - 2; nb[m++] = k - 1; }
    if (k + 1 < 9) nb[m++] = k + 1;
    if (k + 2 < 9) nb[m++] = k + 2;
    const int n = m + 1;

    float g[4], Lc[4][4], tv[4];
    for (int i = 0; i < m; ++i) g[i] = Gsym[nb[i] * 9 + k];

    for (int i = 0; i < m; ++i) {
      for (int j = 0; j <= i; ++j) {
        float sum = Gsym[nb[i] * 9 + nb[j]];
        for (int p = 0; p < j; ++p) sum -= Lc[i][p] * Lc[j][p];
        Lc[i][j] = (i == j) ? sqrtf(sum) : sum / Lc[j][j];
      }
    }
    float s2 = 0.f;
    for (int i = 0; i < m; ++i) {
      float sum = g[i];
      for (int p = 0; p < i; ++p) sum -= Lc[i][p] * tv[p];
      tv[i] = sum / Lc[i][i];
      s2 += tv[i] * tv[i];
    }
    float ar = 0.f;
    for (int i = 0; i < m; ++i) ar += g[i] / sqrtf(Gsym[nb[i] * 9 + nb[i]]);
    ar /= (float)m;

    st[k] = sqrtf(s2) / (ar * (2.0f * (float)n));          // align
    float Gkk = Gsym[k * 9 + k];
    st[9 + k] = sqrtf(fmaxf(Gkk - s2, 0.f)) / sqrtf(Gkk);  // nov
  }
  if (t == 9) {
    float sc = 0.f, sc2 = 0.f;
    for (int i = 0; i < 8; ++i) {
      float nn = sqrtf(Gsym[i * 9 + i]) * sqrtf(Gsym[(i + 1) * 9 + i + 1]);
      nn = fmaxf(nn, 1e-8f);
      float ci = Gsym[i * 9 + i + 1] / nn;
      sc += ci; sc2 += ci * ci;
    }
    float mean = sc * 0.125f;
    st[18] = (sc2 - 8.f * mean * mean) * (1.f / 7.f);
  }
  __syncthreads();

  // all lanes: redundant scalar epilogue from broadcast LDS reads; write w * te
  const float w = valid ? st[18] : 0.f;
  float sa = 0.f, sn = 0.f;
#pragma unroll
  for (int l = 0; l < 9; ++l) { sa += st[l]; sn += st[9 + l]; }
  const float rsa = 1.f / sa, rsn = 1.f / sn;
  float a9[9]; float ss = 0.f;
#pragma unroll
  for (int l = 0; l < 9; ++l) { a9[l] = st[l] * rsa + st[9 + l] * rsn; ss += a9[l]; }
  const float inv = w / ss;

  float4* o = (float4*)wte + (size_t)token * D4 + t;
#pragma unroll
  for (int c = 0; c < 3; ++c) {
    float4 acc = make_float4(0.f, 0.f, 0.f, 0.f);
#pragma unroll
    for (int l = 0; l < 9; ++l) {
      float a = a9[l] * inv;
      float4 p = f[l * 3 + c];
      acc.x += a * p.x; acc.y += a * p.y; acc.z += a * p.z; acc.w += a * p.w;
    }
    o[c * 64] = acc;
  }
  if (t == 0) wv[token] = w;
}

// ---------------- kernel 2: fused pool + final via last-block-done reduction ----------------
// 256 blocks; each writes its 16-token chunk partial; the 32nd finisher per batch
// does the fixed-order final sum (bitwise deterministic — atomics only gate WHO).
__global__ __launch_bounds__(192) void wk_pool2(const float* __restrict__ wte,
                                                const float* __restrict__ wv,
                                                float* __restrict__ P,
                                                float* __restrict__ Pw,
                                                int* __restrict__ cnt,
                                                float* __restrict__ out) {
  const int b = blockIdx.x >> 5;
  const int c = blockIdx.x & 31;
  const int t = threadIdx.x;

  // chunk partial sum over 16 tokens
  float4 a = make_float4(0.f, 0.f, 0.f, 0.f);
  const float4* base = (const float4*)wte + ((size_t)b * S_ + c * CW) * D4 + t;
#pragma unroll 4
  for (int sl = 0; sl < CW; ++sl) {
    float4 p = base[sl * D4];
    a.x += p.x; a.y += p.y; a.z += p.z; a.w += p.w;
  }
  ((float4*)P)[(size_t)blockIdx.x * D4 + t] = a;
  if (t == 0) {
    float ws = 0.f;
#pragma unroll
    for (int i = 0; i < CW; ++i) ws += wv[b * S_ + c * CW + i];
    Pw[blockIdx.x] = ws;
  }

  // release partials, count finished chunks for this batch
  __threadfence();
  __shared__ int lastdone;
  if (t == 0) lastdone = (atomicAdd(&cnt[b], 1) == SCH - 1);
  __syncthreads();
  if (!lastdone) return;
  __threadfence();   // acquire: all 32 partials of batch b now visible

  // final: fixed-order sum over the 32 chunk partials
  float4 n = make_float4(0.f, 0.f, 0.f, 0.f);
  float den = 0.f;
#pragma unroll 4
  for (int cc = 0; cc < SCH; ++cc) {
    float4 p = ((const float4*)P)[((size_t)b * SCH + cc) * D4 + t];
    n.x += p.x; n.y += p.y; n.z += p.z; n.w += p.w;
    den += Pw[b * SCH + cc];
  }
  const float r = 1.f / den;
  ((float4*)out)[b * D4 + t] = make_float4(n.x * r, n.y * r, n.z * r, n.w * r);
}

extern "C" void kernel_launch(void* const* d_in, const int* in_sizes, int n_in,
                              void* d_out, int out_size, void* d_ws, size_t ws_size,
                              hipStream_t stream) {
  const float* hid = (const float*)d_in[0];       // (13, 8, 512, 768) f32
  const int* mask = (const int*)d_in[1];          // (8, 512) i32
  float* out = (float*)d_out;                     // (8, 768) f32

  float* wte = (float*)d_ws;                      // B*S*D  (w * token_emb)
  float* wv  = wte + (size_t)B_ * S_ * D_;        // B*S    (token weights)
  float* P   = wv + B_ * S_;                      // B*SCH*D
  float* Pw  = P + (size_t)B_ * SCH * D_;         // B*SCH
  int*  cnt  = (int*)(Pw + B_ * SCH);             // B counters (zeroed each call)

  hipMemsetAsync(cnt, 0, B_ * sizeof(int), stream);
  wk_token<<<B_ * S_, 64, 0, stream>>>(hid, mask, wte, wv);
  wk_pool2<<<B_ * SCH, 192, 0, stream>>>(wte, wv, P, Pw, cnt, out);
}

// Round 12
// 56.531 us; speedup vs baseline: 1.3875x; 1.3875x over previous
//
#include <hip/hip_runtime.h>

#define B_ 8
#define S_ 512
#define D_ 768
#define D4 (D_/4)                // 192 float4 per token vector
#define LAYER0 4
#define LSTRIDE4 (8*512*768/4)   // float4 between layers
#define SCH 32                   // pooling chunks per batch
#define CW (S_/SCH)              // 16 tokens per chunk

// upper-triangle pair q -> (i,j), i<=j, row-major
__device__ const int QI9[45] = {0,0,0,0,0,0,0,0,0, 1,1,1,1,1,1,1,1, 2,2,2,2,2,2,2,
                                3,3,3,3,3,3, 4,4,4,4,4, 5,5,5,5, 6,6,6, 7,7, 8};
__device__ const int QJ9[45] = {0,1,2,3,4,5,6,7,8, 1,2,3,4,5,6,7,8, 2,3,4,5,6,7,8,
                                3,4,5,6,7,8, 4,5,6,7,8, 5,6,7,8, 6,7,8, 7,8, 8};

__device__ __forceinline__ float dot4(const float4& a, const float4& b) {
  return fmaf(a.x, b.x, fmaf(a.y, b.y, fmaf(a.z, b.z, a.w * b.w)));
}

// 4-lane quad sum on the VALU pipe (DPP quad_perm), no DS ops. Proven in R10.
__device__ __forceinline__ float quad_sum(float v) {
  int x = __builtin_amdgcn_update_dpp(0, __builtin_bit_cast(int, v),
                                      0xB1, 0xF, 0xF, true);   // quad_perm [1,0,3,2]
  v += __builtin_bit_cast(float, x);
  x = __builtin_amdgcn_update_dpp(0, __builtin_bit_cast(int, v),
                                  0x4E, 0xF, 0xF, true);       // quad_perm [2,3,0,1]
  v += __builtin_bit_cast(float, x);
  return v;
}

// ---------------- kernel 1: per-token Gram, 3 dim-chunk passes, low-VGPR ----------------
__global__ __launch_bounds__(64) void wk_token(const float* __restrict__ hid,
                                               const int* __restrict__ mask,
                                               float* __restrict__ wte,
                                               float* __restrict__ wv) {
  const int token = blockIdx.x;        // b*S + s
  const int b = token >> 9;
  const int s = token & (S_ - 1);
  const int t = threadIdx.x;           // 0..63, one wave

  __shared__ float pgl[16][45];        // 2.9 KB after quad pre-reduce
  __shared__ float Gsym[81];
  __shared__ float st[19];             // align[0..8], nov[9..17], var[18]

  // mask is monotone (arange < length): s < len=length-1  <=>  mask[s+1]==1
  const int valid = (s < S_ - 1) ? mask[b * S_ + s + 1] : 0;

  const float4* base = (const float4*)hid
      + (((size_t)LAYER0 * B_ + b) * S_ + s) * D4 + t;

  // G = sum over 3 dim-chunks of F_c F_c^T: only f[9] (36 VGPR) live per pass
#pragma unroll
  for (int c = 0; c < 3; ++c) {
    float4 f[9];
#pragma unroll
    for (int l = 0; l < 9; ++l) f[l] = base[(size_t)l * LSTRIDE4 + c * 64];
    int q = 0;
#pragma unroll
    for (int i = 0; i < 9; ++i) {
#pragma unroll
      for (int j = i; j < 9; ++j) {
        float v = quad_sum(dot4(f[i], f[j]));
        if ((t & 3) == 0) {
          if (c == 0) pgl[t >> 2][q] = v;
          else        pgl[t >> 2][q] += v;   // same-lane DS ordering: no sync needed
        }
        ++q;
      }
    }
    __builtin_amdgcn_sched_barrier(0);  // keep passes separate: caps live VGPRs
  }
  __syncthreads();

  // column sums: lane q (<45) sums 16 rows; 4 accumulators break the FP chain
  if (t < 45) {
    float a0 = 0.f, a1 = 0.f, a2 = 0.f, a3 = 0.f;
#pragma unroll
    for (int r = 0; r < 16; r += 4) {
      a0 += pgl[r][t];     a1 += pgl[r + 1][t];
      a2 += pgl[r + 2][t]; a3 += pgl[r + 3][t];
    }
    float tot = (a0 + a1) + (a2 + a3);
    Gsym[QI9[t] * 9 + QJ9[t]] = tot;
    Gsym[QJ9[t] * 9 + QI9[t]] = tot;
  }
  __syncthreads();

  // lanes 0..8: per-k align/nov via Cholesky; lane 9: cosine variance -> LDS
  if (t < 9) {
    const int k = t;
    int nb[4]; int m = 0;
    if (k >= 2) { nb[m++] = k - 2; nb[m++] = k - 1; }
    if (k + 1 < 9) nb[m++] = k + 1;
    if (k + 2 < 9) nb[m++] = k + 2;
    const int n = m + 1;

    float g[4], Lc[4][4], tv[4];
    for (int i = 0; i < m; ++i) g[i] = Gsym[nb[i] * 9 + k];

    for (int i = 0; i < m; ++i) {
      for (int j = 0; j <= i; ++j) {
        float sum = Gsym[nb[i] * 9 + nb[j]];
        for (int p = 0; p < j; ++p) sum -= Lc[i][p] * Lc[j][p];
        Lc[i][j] = (i == j) ? sqrtf(sum) : sum / Lc[j][j];
      }
    }
    float s2 = 0.f;
    for (int i = 0; i < m; ++i) {
      float sum = g[i];
      for (int p = 0; p < i; ++p) sum -= Lc[i][p] * tv[p];
      tv[i] = sum / Lc[i][i];
      s2 += tv[i] * tv[i];
    }
    float ar = 0.f;
    for (int i = 0; i < m; ++i) ar += g[i] / sqrtf(Gsym[nb[i] * 9 + nb[i]]);
    ar /= (float)m;

    st[k] = sqrtf(s2) / (ar * (2.0f * (float)n));          // align
    float Gkk = Gsym[k * 9 + k];
    st[9 + k] = sqrtf(fmaxf(Gkk - s2, 0.f)) / sqrtf(Gkk);  // nov
  }
  if (t == 9) {
    float sc = 0.f, sc2 = 0.f;
    for (int i = 0; i < 8; ++i) {
      float nn = sqrtf(Gsym[i * 9 + i]) * sqrtf(Gsym[(i + 1) * 9 + i + 1]);
      nn = fmaxf(nn, 1e-8f);
      float ci = Gsym[i * 9 + i + 1] / nn;
      sc += ci; sc2 += ci * ci;
    }
    float mean = sc * 0.125f;
    st[18] = (sc2 - 8.f * mean * mean) * (1.f / 7.f);
  }
  __syncthreads();

  // epilogue: broadcast LDS reads; reload f per chunk from L2/L3 (hot), write w*te
  const float w = valid ? st[18] : 0.f;
  float sa = 0.f, sn = 0.f;
#pragma unroll
  for (int l = 0; l < 9; ++l) { sa += st[l]; sn += st[9 + l]; }
  const float rsa = 1.f / sa, rsn = 1.f / sn;
  float a9[9]; float ss = 0.f;
#pragma unroll
  for (int l = 0; l < 9; ++l) { a9[l] = st[l] * rsa + st[9 + l] * rsn; ss += a9[l]; }
  const float inv = w / ss;

  float4* o = (float4*)wte + (size_t)token * D4 + t;
#pragma unroll
  for (int c = 0; c < 3; ++c) {
    float4 acc = make_float4(0.f, 0.f, 0.f, 0.f);
#pragma unroll
    for (int l = 0; l < 9; ++l) {
      float4 p = base[(size_t)l * LSTRIDE4 + c * 64];
      const float a = a9[l] * inv;
      acc.x += a * p.x; acc.y += a * p.y; acc.z += a * p.z; acc.w += a * p.w;
    }
    o[c * 64] = acc;
  }
  if (t == 0) wv[token] = w;
}

// ---------------- kernel 2: plain partial sums over 16-token chunks (R6 proven) ----------------
__global__ __launch_bounds__(192) void wk_pool(const float* __restrict__ wte,
                                               const float* __restrict__ wv,
                                               float* __restrict__ P,
                                               float* __restrict__ Pw) {
  const int b = blockIdx.x >> 5;
  const int c = blockIdx.x & 31;
  const int t = threadIdx.x;

  float4 a = make_float4(0.f, 0.f, 0.f, 0.f);
  const float4* base = (const float4*)wte + ((size_t)b * S_ + c * CW) * D4 + t;
#pragma unroll 4
  for (int sl = 0; sl < CW; ++sl) {
    float4 p = base[sl * D4];
    a.x += p.x; a.y += p.y; a.z += p.z; a.w += p.w;
  }
  ((float4*)P)[(size_t)blockIdx.x * D4 + t] = a;
  if (t == 0) {
    float ws = 0.f;
#pragma unroll
    for (int i = 0; i < CW; ++i) ws += wv[b * S_ + c * CW + i];
    Pw[blockIdx.x] = ws;
  }
}

// ---------------- kernel 3: combine partials, divide by weight sum (R6 proven) ----------------
__global__ __launch_bounds__(256) void wk_pool_final(const float* __restrict__ P,
                                                     const float* __restrict__ Pw,
                                                     float* __restrict__ out) {
  const int i = blockIdx.x * 256 + threadIdx.x;   // 0 .. B*D4-1 = 1535
  const int b = i / D4;
  const int d4 = i % D4;
  float n0 = 0.f, n1 = 0.f, n2 = 0.f, n3 = 0.f, den = 0.f;
#pragma unroll
  for (int c = 0; c < SCH; ++c) {
    float4 p = ((const float4*)P)[((size_t)b * SCH + c) * D4 + d4];
    n0 += p.x; n1 += p.y; n2 += p.z; n3 += p.w;
    den += Pw[b * SCH + c];
  }
  float inv = 1.f / den;
  ((float4*)out)[i] = make_float4(n0 * inv, n1 * inv, n2 * inv, n3 * inv);
}

extern "C" void kernel_launch(void* const* d_in, const int* in_sizes, int n_in,
                              void* d_out, int out_size, void* d_ws, size_t ws_size,
                              hipStream_t stream) {
  const float* hid = (const float*)d_in[0];       // (13, 8, 512, 768) f32
  const int* mask = (const int*)d_in[1];          // (8, 512) i32
  float* out = (float*)d_out;                     // (8, 768) f32

  float* wte = (float*)d_ws;                      // B*S*D  (w * token_emb)
  float* wv  = wte + (size_t)B_ * S_ * D_;        // B*S    (token weights)
  float* P   = wv + B_ * S_;                      // B*SCH*D
  float* Pw  = P + (size_t)B_ * SCH * D_;         // B*SCH

  wk_token<<<B_ * S_, 64, 0, stream>>>(hid, mask, wte, wv);
  wk_pool<<<B_ * SCH, 192, 0, stream>>>(wte, wv, P, Pw);
  wk_pool_final<<<(B_ * D4 + 255) / 256, 256, 0, stream>>>(P, Pw, out);
}